// Round 1
// baseline (1461.619 us; speedup 1.0000x reference)
//
#include <hip/hip_runtime.h>
#include <math.h>

// Problem constants (idx == 10 branch; shapes fixed by setup_inputs)
#define L_    3136          // 56*56
#define R_    25088         // 8*L
#define C_    256
#define K4_   512
#define MATF  6422528       // 256 * R_

enum { GM_BIAS = 0, GM_CONV = 1, GM_GELU = 2 };

#define BM 128
#define BN 64
#define BK 16

// C[M][R_] = W[M][K] * X[K][R_]  (X row-major [K][R_]; CONV mode reads a4 [b][K4][L])
template<int MODE>
__global__ __launch_bounds__(256)
void gemm_k(const float* __restrict__ Wm, const float* __restrict__ X,
            float* __restrict__ Y, const float* __restrict__ bias,
            const float* __restrict__ bnw, const float* __restrict__ bnb,
            const float* __restrict__ pos, int K)
{
    __shared__ float Ws[BK][BM + 4];
    __shared__ float Xs[BK][BN + 4];
    const int tid = threadIdx.x;
    const int r0 = blockIdx.x * BN;
    const int m0 = blockIdx.y * BM;

    const float* Xbase;
    int ldx, s_off = 0;
    if (MODE == GM_CONV) {
        int b = r0 / L_;                 // BN=64 tiles never cross b (3136 % 64 == 0)
        s_off = r0 - b * L_;
        Xbase = X + (size_t)b * K4_ * L_ + s_off;
        ldx = L_;
    } else {
        Xbase = X + r0;
        ldx = R_;
    }

    const int tm  = tid >> 4;            // 0..15 -> rows tm*8..tm*8+7
    const int tn  = tid & 15;            // 0..15 -> cols tn*4..tn*4+3
    const int lm  = tid >> 1;            // W-load row 0..127
    const int lk8 = (tid & 1) << 3;      // 0 or 8
    const int xk  = tid >> 4;            // X-load k row 0..15
    const int xn4 = (tid & 15) << 2;     // 0..60

    float acc[8][4];
    #pragma unroll
    for (int i = 0; i < 8; i++)
        #pragma unroll
        for (int j = 0; j < 4; j++) acc[i][j] = 0.f;

    for (int k0 = 0; k0 < K; k0 += BK) {
        const float* wp = Wm + (size_t)(m0 + lm) * K + k0 + lk8;
        float4 w0 = *reinterpret_cast<const float4*>(wp);
        float4 w1 = *reinterpret_cast<const float4*>(wp + 4);
        Ws[lk8+0][lm] = w0.x; Ws[lk8+1][lm] = w0.y;
        Ws[lk8+2][lm] = w0.z; Ws[lk8+3][lm] = w0.w;
        Ws[lk8+4][lm] = w1.x; Ws[lk8+5][lm] = w1.y;
        Ws[lk8+6][lm] = w1.z; Ws[lk8+7][lm] = w1.w;
        float4 xv = *reinterpret_cast<const float4*>(Xbase + (size_t)(k0 + xk) * ldx + xn4);
        *reinterpret_cast<float4*>(&Xs[xk][xn4]) = xv;
        __syncthreads();
        #pragma unroll
        for (int k = 0; k < BK; k++) {
            float4 a0 = *reinterpret_cast<const float4*>(&Ws[k][tm*8]);
            float4 a1 = *reinterpret_cast<const float4*>(&Ws[k][tm*8+4]);
            float4 bv = *reinterpret_cast<const float4*>(&Xs[k][tn*4]);
            float av[8] = {a0.x,a0.y,a0.z,a0.w,a1.x,a1.y,a1.z,a1.w};
            float bb[4] = {bv.x,bv.y,bv.z,bv.w};
            #pragma unroll
            for (int i = 0; i < 8; i++)
                #pragma unroll
                for (int j = 0; j < 4; j++)
                    acc[i][j] = fmaf(av[i], bb[j], acc[i][j]);
        }
        __syncthreads();
    }

    #pragma unroll
    for (int i = 0; i < 8; i++) {
        int m = m0 + tm*8 + i;
        float bsv = bias[m];
        float4 o;
        #pragma unroll
        for (int j = 0; j < 4; j++) {
            float v = acc[i][j] + bsv;
            if (MODE == GM_CONV) {
                // BatchNorm eval: /sqrt(1+1e-5) * w + b, then +pos (fused for K/V input)
                v = v * 0.9999950000374997f * bnw[m] + bnb[m];
                v += pos[(size_t)m * L_ + (s_off + tn*4 + j)];
            } else if (MODE == GM_GELU) {
                v = 0.5f * v * (1.f + erff(v * 0.7071067811865475f));
            }
            (&o.x)[j] = v;
        }
        *reinterpret_cast<float4*>(Y + (size_t)m * R_ + r0 + tn*4) = o;
    }
}

// pos[c][l]: c<64: sin(y*om) | <128: cos(y*om) | <192: sin(x*om) | <256: cos(x*om)
__global__ __launch_bounds__(256)
void pos_k(float* __restrict__ pos)
{
    int c = blockIdx.x;
    int q = c >> 6, t = c & 63;
    float om = exp2f(-(float)t * (13.287712379549449f / 64.f));  // 10000^(-t/64)
    for (int l = threadIdx.x; l < L_; l += 256) {
        int y = l / 56, x = l - y * 56;
        float arg = (q < 2 ? (float)y : (float)x) * om;
        pos[(size_t)c * L_ + l] = (q & 1) ? cosf(arg) : sinf(arg);
    }
}

// avgpool2(a3) -> a3d[c][r] (residual) and xq[c][r] = a3d + pos
__global__ __launch_bounds__(256)
void pool_k(const float* __restrict__ a3, const float* __restrict__ pos,
            float* __restrict__ a3d, float* __restrict__ xq)
{
    int b = blockIdx.x >> 8;
    int c = blockIdx.x & 255;
    const float* src = a3 + (size_t)(b * C_ + c) * 12544;
    float* pd = a3d + (size_t)c * R_ + (size_t)b * L_;
    float* pq = xq  + (size_t)c * R_ + (size_t)b * L_;
    const float* pp = pos + (size_t)c * L_;
    for (int l = threadIdx.x; l < L_; l += 256) {
        int y = l / 56, x = l - y * 56;
        const float* sp = src + (2*y) * 112 + 2*x;
        float2 lo = *reinterpret_cast<const float2*>(sp);
        float2 hi = *reinterpret_cast<const float2*>(sp + 112);
        float v = (lo.x + lo.y + hi.x + hi.y) * 0.25f;
        pd[l] = v;
        pq[l] = v + pp[l];
    }
}

// In-place LayerNorm (eps 1e-5) over channel dim then l2-normalize (max(n,1e-4)).
__global__ __launch_bounds__(256)
void ln_l2_k(float* __restrict__ X, const float* __restrict__ wt, const float* __restrict__ bt)
{
    __shared__ float red[4][64];
    __shared__ float red2[4][64];
    int tid = threadIdx.x;
    int rr = tid & 63, og = tid >> 6;
    size_t r = (size_t)blockIdx.x * 64 + rr;
    float s1 = 0.f, s2 = 0.f;
    for (int j = 0; j < 64; j++) {
        float v = X[(size_t)(og*64 + j) * R_ + r];
        s1 += v; s2 = fmaf(v, v, s2);
    }
    red[og][rr] = s1; red2[og][rr] = s2;
    __syncthreads();
    float mu  = (red[0][rr]+red[1][rr]+red[2][rr]+red[3][rr]) * (1.f/256.f);
    float var = (red2[0][rr]+red2[1][rr]+red2[2][rr]+red2[3][rr]) * (1.f/256.f) - mu*mu;
    float rstd = rsqrtf(var + 1e-5f);
    __syncthreads();                       // protect red before reuse
    float t2 = 0.f;
    for (int j = 0; j < 64; j++) {
        int o = og*64 + j;
        float v = X[(size_t)o * R_ + r];
        float y = (v - mu) * rstd * wt[o] + bt[o];
        t2 = fmaf(y, y, t2);
    }
    red[og][rr] = t2;
    __syncthreads();
    float nrm = sqrtf(red[0][rr]+red[1][rr]+red[2][rr]+red[3][rr]);
    float scale = 1.f / fmaxf(nrm, 1e-4f);
    for (int j = 0; j < 64; j++) {
        int o = og*64 + j;
        size_t ix = (size_t)o * R_ + r;
        float v = X[ix];
        float y = (v - mu) * rstd * wt[o] + bt[o];
        X[ix] = y * scale;
    }
}

// In-place X = res + LayerNorm(X)
__global__ __launch_bounds__(256)
void ln_res_k(float* __restrict__ X, const float* __restrict__ res,
              const float* __restrict__ wt, const float* __restrict__ bt)
{
    __shared__ float red[4][64];
    __shared__ float red2[4][64];
    int tid = threadIdx.x;
    int rr = tid & 63, og = tid >> 6;
    size_t r = (size_t)blockIdx.x * 64 + rr;
    float s1 = 0.f, s2 = 0.f;
    for (int j = 0; j < 64; j++) {
        float v = X[(size_t)(og*64 + j) * R_ + r];
        s1 += v; s2 = fmaf(v, v, s2);
    }
    red[og][rr] = s1; red2[og][rr] = s2;
    __syncthreads();
    float mu  = (red[0][rr]+red[1][rr]+red[2][rr]+red[3][rr]) * (1.f/256.f);
    float var = (red2[0][rr]+red2[1][rr]+red2[2][rr]+red2[3][rr]) * (1.f/256.f) - mu*mu;
    float rstd = rsqrtf(var + 1e-5f);
    for (int j = 0; j < 64; j++) {
        int o = og*64 + j;
        size_t ix = (size_t)o * R_ + r;
        float v = X[ix];
        X[ix] = res[ix] + (v - mu) * rstd * wt[o] + bt[o];
    }
}

// Partial KV: kvp[n][slab][d][m] = sum_{l in slab} (d<32?cw:sw)[l]*K[l][d&31]*V[l][m]
__global__ __launch_bounds__(256)
void kv_part_k(const float* __restrict__ Kt, const float* __restrict__ Vt,
               float* __restrict__ kvp)
{
    __shared__ float kl[64][33];
    __shared__ float vl[64][33];
    __shared__ float cwl[64], swl[64];
    int slab = blockIdx.x;               // 0..6 (448 l each)
    int n = blockIdx.y;                  // 0..63
    int b = n >> 3, h = n & 7;
    int tid = threadIdx.x;
    int lane = tid & 63, grp = tid >> 6;
    int d = tid >> 2;                    // 0..63
    int m0 = (tid & 3) * 8;
    float acc[8] = {0,0,0,0,0,0,0,0};
    size_t base = (size_t)(h * 32) * R_ + (size_t)b * L_;
    for (int ch = 0; ch < 7; ch++) {
        int l0 = slab * 448 + ch * 64;
        #pragma unroll
        for (int j = 0; j < 8; j++) {
            int dd = grp * 8 + j;
            kl[lane][dd] = Kt[base + (size_t)dd * R_ + l0 + lane];
            vl[lane][dd] = Vt[base + (size_t)dd * R_ + l0 + lane];
        }
        if (tid < 64) {
            float wi = (float)(l0 + tid + 1) * (1.f / 3136.f);
            cwl[tid] = cosf(wi); swl[tid] = sinf(wi);
        }
        __syncthreads();
        for (int l = 0; l < 64; l++) {
            float kvv = (d < 32 ? cwl[l] : swl[l]) * kl[l][d & 31];
            #pragma unroll
            for (int j = 0; j < 8; j++)
                acc[j] = fmaf(kvv, vl[l][m0 + j], acc[j]);
        }
        __syncthreads();
    }
    float* out = kvp + ((size_t)(n * 7 + slab)) * 2048 + d * 32 + m0;
    #pragma unroll
    for (int j = 0; j < 8; j++) out[j] = acc[j];
}

__global__ __launch_bounds__(256)
void kv_red_k(const float* __restrict__ kvp, float* __restrict__ kv)
{
    int idx = blockIdx.x * 256 + threadIdx.x;   // < 64*2048
    int n = idx >> 11, dm = idx & 2047;
    float s = 0.f;
    #pragma unroll
    for (int t = 0; t < 7; t++) s += kvp[((size_t)(n * 7 + t)) * 2048 + dm];
    kv[idx] = s;
}

// attn[c=h*32+m][r] = rmsnorm_head( cw*Q.KVtop + sw*Q.KVbot )
__global__ __launch_bounds__(256)
void attn_k(const float* __restrict__ Q, const float* __restrict__ kv,
            const float* __restrict__ rmsw, float* __restrict__ attn)
{
    __shared__ float kvl[2048];
    int h = blockIdx.y, b = blockIdx.z;
    int tid = threadIdx.x;
    int n = b * 8 + h;
    for (int i = tid; i < 2048; i += 256) kvl[i] = kv[(size_t)n * 2048 + i];
    __syncthreads();
    int l = blockIdx.x * 256 + tid;
    if (l >= L_) return;
    size_t r = (size_t)b * L_ + l;
    float qd[32];
    #pragma unroll
    for (int dd = 0; dd < 32; dd++) qd[dd] = Q[((size_t)(h*32 + dd)) * R_ + r];
    float wi = (float)(l + 1) * (1.f / 3136.f);
    float cw = cosf(wi), sw = sinf(wi);
    float val[32]; float ss = 0.f;
    #pragma unroll
    for (int m = 0; m < 32; m++) {
        float s1 = 0.f, s2 = 0.f;
        #pragma unroll
        for (int dd = 0; dd < 32; dd++) {
            s1 = fmaf(qd[dd], kvl[dd*32 + m], s1);
            s2 = fmaf(qd[dd], kvl[(dd+32)*32 + m], s2);
        }
        float v = cw * s1 + sw * s2;
        val[m] = v; ss = fmaf(v, v, ss);
    }
    float rinv = rsqrtf(ss * (1.f/32.f) + 1e-6f);
    #pragma unroll
    for (int m = 0; m < 32; m++)
        attn[((size_t)(h*32 + m)) * R_ + r] = rmsw[m] * val[m] * rinv;
}

__device__ __forceinline__ void bil_coord(int o, int lim, int& i0, int& i1, float& t)
{
    float f = o * 0.5f - 0.25f;          // half-pixel, scale 2 (align_corners=False)
    float fl = floorf(f);
    t = f - fl;
    int i = (int)fl;
    i0 = i < 0 ? 0 : (i > lim ? lim : i);
    int ip = i + 1;
    i1 = ip < 0 ? 0 : (ip > lim ? lim : ip);
}

__global__ __launch_bounds__(256)
void up_a3_k(const float* __restrict__ out2, const float* __restrict__ a3,
             float* __restrict__ out)
{
    unsigned idx = blockIdx.x * 256u + threadIdx.x;   // < 25690112
    int xo = idx % 112;
    unsigned t1 = idx / 112;
    int yo = t1 % 112;
    unsigned t2 = t1 / 112;
    int c = t2 & 255;
    int b = t2 >> 8;
    int x0, x1, y0, y1; float tx, ty;
    bil_coord(xo, 55, x0, x1, tx);
    bil_coord(yo, 55, y0, y1, ty);
    const float* src = out2 + (size_t)c * R_ + (size_t)b * L_;
    float v00 = src[y0*56 + x0], v01 = src[y0*56 + x1];
    float v10 = src[y1*56 + x0], v11 = src[y1*56 + x1];
    float v = (1.f-ty) * ((1.f-tx)*v00 + tx*v01) + ty * ((1.f-tx)*v10 + tx*v11);
    out[idx] = v * a3[idx];
}

__global__ __launch_bounds__(256)
void up_a4_k(const float* __restrict__ a4, float* __restrict__ out)
{
    unsigned idx = blockIdx.x * 256u + threadIdx.x;   // < 51380224
    int xo = idx % 112;
    unsigned t1 = idx / 112;
    int yo = t1 % 112;
    unsigned t2 = t1 / 112;
    int c = t2 & 511;
    int b = t2 >> 9;
    int x0, x1, y0, y1; float tx, ty;
    bil_coord(xo, 55, x0, x1, tx);
    bil_coord(yo, 55, y0, y1, ty);
    const float* src = a4 + (size_t)(b * 512 + c) * 3136;
    float v00 = src[y0*56 + x0], v01 = src[y0*56 + x1];
    float v10 = src[y1*56 + x0], v11 = src[y1*56 + x1];
    out[idx] = (1.f-ty) * ((1.f-tx)*v00 + tx*v01) + ty * ((1.f-tx)*v10 + tx*v11);
}

extern "C" void kernel_launch(void* const* d_in, const int* in_sizes, int n_in,
                              void* d_out, int out_size, void* d_ws, size_t ws_size,
                              hipStream_t stream)
{
    const float* a3     = (const float*)d_in[0];
    const float* a4     = (const float*)d_in[1];
    const float* conv_w = (const float*)d_in[2];
    const float* conv_b = (const float*)d_in[3];
    const float* bn_w   = (const float*)d_in[4];
    const float* bn_b   = (const float*)d_in[5];
    const float* q_w    = (const float*)d_in[6];
    const float* q_b    = (const float*)d_in[7];
    const float* q_ln_w = (const float*)d_in[8];
    const float* q_ln_b = (const float*)d_in[9];
    const float* k_w    = (const float*)d_in[10];
    const float* k_b    = (const float*)d_in[11];
    const float* k_ln_w = (const float*)d_in[12];
    const float* k_ln_b = (const float*)d_in[13];
    const float* v_w    = (const float*)d_in[14];
    const float* v_b    = (const float*)d_in[15];
    const float* o_w    = (const float*)d_in[16];
    const float* o_b    = (const float*)d_in[17];
    const float* rms_w  = (const float*)d_in[18];
    const float* l1_w   = (const float*)d_in[19];
    const float* l1_b   = (const float*)d_in[20];
    const float* l2_w   = (const float*)d_in[21];
    const float* l2_b   = (const float*)d_in[22];
    const float* n1_w   = (const float*)d_in[23];
    const float* n1_b   = (const float*)d_in[24];
    const float* n2_w   = (const float*)d_in[25];
    const float* n2_b   = (const float*)d_in[26];
    (void)in_sizes; (void)n_in; (void)out_size;

    // workspace plan (floats): pos | A a3d | B xq | C xkv | D q | E k | F v/ffnout/out2
    //                          | G attn | H olin/out1 | kvp | kv    (~213 MB)
    float* ws  = (float*)d_ws;
    float* pos = ws;
    float* A   = ws + 802816;
    float* Bq  = A  + MATF;
    float* Cx  = Bq + MATF;
    float* Dq  = Cx + MATF;
    float* Ek  = Dq + MATF;
    float* Fv  = Ek + MATF;
    float* Ga  = Fv + MATF;
    float* Ho  = Ga + MATF;
    float* ffn = Bq;               // 4*MATF spanning B..E (all dead by FFN time)
    float* kvp = Ho + MATF;        // 64*7*2048
    float* kvb = kvp + 917504;     // 64*2048
    if (ws_size < (size_t)(53231616) * 4) return;  // insufficient scratch

    pos_k <<<256, 256, 0, stream>>>(pos);
    pool_k<<<2048, 256, 0, stream>>>(a3, pos, A, Bq);
    gemm_k<GM_CONV><<<dim3(392, 2), 256, 0, stream>>>(conv_w, a4, Cx, conv_b, bn_w, bn_b, pos, 512);
    gemm_k<GM_BIAS><<<dim3(392, 2), 256, 0, stream>>>(q_w, Bq, Dq, q_b, nullptr, nullptr, nullptr, 256);
    ln_l2_k<<<392, 256, 0, stream>>>(Dq, q_ln_w, q_ln_b);
    gemm_k<GM_BIAS><<<dim3(392, 2), 256, 0, stream>>>(k_w, Cx, Ek, k_b, nullptr, nullptr, nullptr, 256);
    ln_l2_k<<<392, 256, 0, stream>>>(Ek, k_ln_w, k_ln_b);
    gemm_k<GM_BIAS><<<dim3(392, 2), 256, 0, stream>>>(v_w, Cx, Fv, v_b, nullptr, nullptr, nullptr, 256);
    kv_part_k<<<dim3(7, 64), 256, 0, stream>>>(Ek, Fv, kvp);
    kv_red_k<<<512, 256, 0, stream>>>(kvp, kvb);
    attn_k<<<dim3(13, 8, 8), 256, 0, stream>>>(Dq, kvb, rms_w, Ga);
    gemm_k<GM_BIAS><<<dim3(392, 2), 256, 0, stream>>>(o_w, Ga, Ho, o_b, nullptr, nullptr, nullptr, 256);
    ln_res_k<<<392, 256, 0, stream>>>(Ho, A, n1_w, n1_b);
    gemm_k<GM_GELU><<<dim3(392, 8), 256, 0, stream>>>(l1_w, Ho, ffn, l1_b, nullptr, nullptr, nullptr, 256);
    gemm_k<GM_BIAS><<<dim3(392, 2), 256, 0, stream>>>(l2_w, ffn, Fv, l2_b, nullptr, nullptr, nullptr, 1024);
    ln_res_k<<<392, 256, 0, stream>>>(Fv, Ho, n2_w, n2_b);
    up_a3_k<<<100352, 256, 0, stream>>>(Fv, a3, (float*)d_out);
    up_a4_k<<<200704, 256, 0, stream>>>(a4, (float*)d_out + 25690112);
}